// Round 4
// baseline (516.874 us; speedup 1.0000x reference)
//
#include <hip/hip_runtime.h>

// Problem: b=4, c=256, ci=128, h=w=64 (HW=4096), field=7, kk=49.
// I/O dtype: fp32 (per reference setup_inputs/output). d_out = 16 MB.
//
// ZERO d_ws usage. Staging plan, all inside d_out (float units):
//   phase 1: phi fp32 [4][128][4096]           @ out_f [0, 2097152)        (8 MB)
//   phase 2: scores fp32 slots (64 f/pixel)    @ out_f [2097152, 3145728)  (4 MB)
//            slot for (b,s): floats (b*4096+s)*64 .. +64, first 49 used;
//            theta computed on the fly, never materialized
//   phase 3: softmax in place over h (reference softmax axis=1)
//   phase 4: g fp32 overwrites phi             @ out_f [0, 2097152)
//   phase 5: aggregate -> y bf16 [4][4096][128]@ bytes [12M, 16M)
//   phase 6: maskconv b=0,1 -> out_f [0, 2097152)        (reads y b=0,1)
//   phase 7: copy y b=2,3 (bytes [14M,16M)) -> x batch-0 region (dead, 2 MB)
//   phase 8: maskconv b=2,3 -> out_f [2097152, 4194304)  (reads y from x scratch)

__device__ __forceinline__ float bf2f(unsigned short u) {
    union { unsigned int i; float f; } v; v.i = ((unsigned int)u) << 16; return v.f;
}
__device__ __forceinline__ unsigned short f2bf(float f) {
    union { float f; unsigned int i; } v; v.f = f;
    unsigned int r = v.i + 0x7FFFu + ((v.i >> 16) & 1u);
    return (unsigned short)(r >> 16);
}

// ---------------------------------------------------------------------------
// conv1x1: dst[b,n,p] = sum_k W[n,k] * x[b,k,p], n in [0,128), K=256.
// BM=64 x BN=64 x BK=16, 256 threads, 4x4 microtile. Used for phi and g.
// ---------------------------------------------------------------------------
__global__ __launch_bounds__(256) void conv1x1_kernel(
    const float* __restrict__ x,
    const float* __restrict__ W,
    float* __restrict__ dst)
{
    const int tid = threadIdx.x;
    const int pt = blockIdx.x;   // 64 pixel tiles
    const int nt = blockIdx.y;   // 2 row tiles
    const int b  = blockIdx.z;
    const int nrow0 = nt * 64;

    __shared__ __align__(16) float sW[16 * 68];
    __shared__ __align__(16) float sX[16 * 68];

    const int tx = tid & 15;
    const int ty = tid >> 4;
    float acc[4][4] = {};

    for (int kt = 0; kt < 16; ++kt) {
        #pragma unroll
        for (int e = 0; e < 4; ++e) {
            int lin = tid + e * 256;
            int kk = lin & 15, nn = lin >> 4;
            sW[kk * 68 + nn] = W[(nrow0 + nn) * 256 + kt * 16 + kk];
        }
        #pragma unroll
        for (int e = 0; e < 4; ++e) {
            int lin = tid + e * 256;
            int pp = lin & 63, kk = lin >> 6;
            sX[kk * 68 + pp] = x[(b * 256 + kt * 16 + kk) * 4096 + pt * 64 + pp];
        }
        __syncthreads();
        #pragma unroll
        for (int kk = 0; kk < 16; ++kk) {
            const float4 wv = *reinterpret_cast<const float4*>(&sW[kk * 68 + ty * 4]);
            const float4 xv = *reinterpret_cast<const float4*>(&sX[kk * 68 + tx * 4]);
            const float wr[4] = {wv.x, wv.y, wv.z, wv.w};
            const float xr[4] = {xv.x, xv.y, xv.z, xv.w};
            #pragma unroll
            for (int r = 0; r < 4; ++r)
                #pragma unroll
                for (int e = 0; e < 4; ++e)
                    acc[r][e] = fmaf(wr[r], xr[e], acc[r][e]);
        }
        __syncthreads();
    }

    const int p0 = pt * 64 + tx * 4;
    #pragma unroll
    for (int r = 0; r < 4; ++r) {
        float4 v = make_float4(acc[r][0], acc[r][1], acc[r][2], acc[r][3]);
        *reinterpret_cast<float4*>(&dst[(b * 128 + nrow0 + ty * 4 + r) * 4096 + p0]) = v;
    }
}

// ---------------------------------------------------------------------------
// scores[b,s,t] = sum_cc theta[b,s,cc] * PhiPatch(F = s*6272 + cc*49 + t)
// theta on the fly: th[cc] = sum_k w_theta[cc,k] * x[b,k,s] (fp32).
// Patch decode (raw-reshape scramble): ch=F>>12, p=F&4095, c0=ch/49,
// kh=(ch%49)/7, kw=(ch%49)%7, value = phi[b,c0,(p>>6)+kh-3,(p&63)+kw-3],
// zero outside the image. One block per (b,s).
// ---------------------------------------------------------------------------
__global__ __launch_bounds__(256) void scores_kernel(
    const float* __restrict__ x,
    const float* __restrict__ w_theta,
    const float* __restrict__ phi,
    float* __restrict__ scores)
{
    const int s = blockIdx.x;
    const int b = blockIdx.y;
    const int tid = threadIdx.x;

    __shared__ float xv[256];
    __shared__ float th[128];

    xv[tid] = x[(b * 256 + tid) * 4096 + s];
    __syncthreads();

    if (tid < 128) {
        const float4* __restrict__ wr =
            reinterpret_cast<const float4*>(w_theta + tid * 256);
        float a = 0.f;
        #pragma unroll 8
        for (int kb = 0; kb < 64; ++kb) {
            float4 w4 = wr[kb];
            a = fmaf(w4.x, xv[kb * 4 + 0], a);
            a = fmaf(w4.y, xv[kb * 4 + 1], a);
            a = fmaf(w4.z, xv[kb * 4 + 2], a);
            a = fmaf(w4.w, xv[kb * 4 + 3], a);
        }
        th[tid] = a;
    }
    __syncthreads();

    if (tid < 196) {
        const int t = tid >> 2;
        const int q = tid & 3;
        const float* __restrict__ phib = phi + b * 524288;
        const int base = s * 6272 + t;
        float acc = 0.f;
        #pragma unroll 4
        for (int cc = q * 32; cc < q * 32 + 32; ++cc) {
            int F = base + cc * 49;
            int ch = F >> 12;
            int p = F & 4095;
            int c0 = ch / 49;
            int k = ch - c0 * 49;
            int kh = k / 7;
            int kw = k - kh * 7;
            int sy = (p >> 6) + kh - 3;
            int sx = (p & 63) + kw - 3;
            float v = 0.f;
            if ((unsigned)sy < 64u && (unsigned)sx < 64u)
                v = phib[c0 * 4096 + sy * 64 + sx];
            acc = fmaf(th[cc], v, acc);
        }
        acc += __shfl_down(acc, 2, 4);
        acc += __shfl_down(acc, 1, 4);
        if (q == 0) scores[(b * 4096 + s) * 64 + t] = acc;
    }
}

// ---------------------------------------------------------------------------
// softmax over h (reference axis=1): for fixed (b,j,t) normalize over i in
// [0,64). One 64-lane wave per group, in place on the fp32 slots.
// ---------------------------------------------------------------------------
__global__ __launch_bounds__(256) void softmax_kernel(float* __restrict__ scores)
{
    const int g = blockIdx.x * 4 + (threadIdx.x >> 6);   // < 12544 = 4*64*49
    const int lane = threadIdx.x & 63;                   // = i (h index)
    const int b = g / 3136;
    const int rem = g - b * 3136;
    const int j = rem / 49;
    const int t = rem - j * 49;

    const int idx = (b * 4096 + lane * 64 + j) * 64 + t;
    float v = scores[idx];

    float m = v;
    #pragma unroll
    for (int o = 32; o > 0; o >>= 1) m = fmaxf(m, __shfl_xor(m, o, 64));
    float e = __expf(v - m);
    float sum = e;
    #pragma unroll
    for (int o = 32; o > 0; o >>= 1) sum += __shfl_xor(sum, o, 64);
    scores[idx] = e / sum;
}

// ---------------------------------------------------------------------------
// aggregate: y[b,s,cc] = sum_t attn[b,s,t] * GPatch(F = s*6272 + t*128 + cc)
// Same flat-decode scramble, g-side layout. y stored bf16 (internal only).
// ---------------------------------------------------------------------------
__global__ __launch_bounds__(128) void aggregate_kernel(
    const float* __restrict__ scores,
    const float* __restrict__ g,
    unsigned short* __restrict__ y_bf)
{
    const int s = blockIdx.x;
    const int b = blockIdx.y;
    const int cc = threadIdx.x;

    __shared__ float at[49];
    if (cc < 49) at[cc] = scores[(b * 4096 + s) * 64 + cc];
    __syncthreads();

    const float* __restrict__ gb = g + b * 524288;
    const int base = s * 6272 + cc;
    float acc = 0.f;
    #pragma unroll 7
    for (int t = 0; t < 49; ++t) {
        int G = base + t * 128;
        int ch = G >> 12;
        int p = G & 4095;
        int c0 = ch / 49;
        int k = ch - c0 * 49;
        int kh = k / 7;
        int kw = k - kh * 7;
        int sy = (p >> 6) + kh - 3;
        int sx = (p & 63) + kw - 3;
        float v = 0.f;
        if ((unsigned)sy < 64u && (unsigned)sx < 64u)
            v = gb[c0 * 4096 + sy * 64 + sx];
        acc = fmaf(at[t], v, acc);
    }
    y_bf[(b * 4096 + s) * 128 + cc] = f2bf(acc);
}

// ---------------------------------------------------------------------------
// maskconv: out[b,o,p] = x[b,o,p] + sum_cc w_mask[o,cc] * y[b,p,cc]
// for b = b0 + blockIdx.z (two batches per launch); y_src indexed with the
// LOCAL batch index. BM=64 x BN=64 x BK=16, K=128. fp32 out.
// ---------------------------------------------------------------------------
__global__ __launch_bounds__(256) void maskconv_kernel(
    const float* __restrict__ x,
    const float* __restrict__ w_mask,
    const unsigned short* __restrict__ y_src,
    int b0,
    float* __restrict__ out)
{
    const int tid = threadIdx.x;
    const int pt = blockIdx.x;   // 64
    const int ot = blockIdx.y;   // 4
    const int bl = blockIdx.z;   // 0..1 local
    const int b  = b0 + bl;

    __shared__ __align__(16) float sW[16 * 68];
    __shared__ __align__(16) float sX[16 * 68];

    const int tx = tid & 15;
    const int ty = tid >> 4;
    float acc[4][4] = {};

    for (int kt = 0; kt < 8; ++kt) {
        #pragma unroll
        for (int e = 0; e < 4; ++e) {
            int lin = tid + e * 256;
            int kk = lin & 15, nn = lin >> 4;
            sW[kk * 68 + nn] = w_mask[(ot * 64 + nn) * 128 + kt * 16 + kk];
        }
        #pragma unroll
        for (int e = 0; e < 4; ++e) {
            int lin = tid + e * 256;
            int kk = lin & 15, pp = lin >> 4;
            sX[kk * 68 + pp] =
                bf2f(y_src[(bl * 4096 + pt * 64 + pp) * 128 + kt * 16 + kk]);
        }
        __syncthreads();
        #pragma unroll
        for (int kk = 0; kk < 16; ++kk) {
            const float4 wv = *reinterpret_cast<const float4*>(&sW[kk * 68 + ty * 4]);
            const float4 xv = *reinterpret_cast<const float4*>(&sX[kk * 68 + tx * 4]);
            const float wr[4] = {wv.x, wv.y, wv.z, wv.w};
            const float xr[4] = {xv.x, xv.y, xv.z, xv.w};
            #pragma unroll
            for (int r = 0; r < 4; ++r)
                #pragma unroll
                for (int e = 0; e < 4; ++e)
                    acc[r][e] = fmaf(wr[r], xr[e], acc[r][e]);
        }
        __syncthreads();
    }

    const int p0 = pt * 64 + tx * 4;
    #pragma unroll
    for (int r = 0; r < 4; ++r) {
        const int o = ot * 64 + ty * 4 + r;
        const int ofs = (b * 256 + o) * 4096 + p0;
        const float4 xr4 = *reinterpret_cast<const float4*>(&x[ofs]);
        float4 v = make_float4(acc[r][0] + xr4.x, acc[r][1] + xr4.y,
                               acc[r][2] + xr4.z, acc[r][3] + xr4.w);
        *reinterpret_cast<float4*>(&out[ofs]) = v;
    }
}

// 2 MB copy: y slots of batches 2,3 -> x batch-0 scratch. 131072 uint4's.
__global__ __launch_bounds__(256) void copy2mb_kernel(
    const uint4* __restrict__ src, uint4* __restrict__ dst)
{
    const int i = blockIdx.x * 256 + threadIdx.x;
    dst[i] = src[i];
}

extern "C" void kernel_launch(void* const* d_in, const int* in_sizes, int n_in,
                              void* d_out, int out_size, void* d_ws, size_t ws_size,
                              hipStream_t stream) {
    const float* x       = (const float*)d_in[0];
    const float* w_phi   = (const float*)d_in[1];
    const float* w_theta = (const float*)d_in[2];
    const float* w_g     = (const float*)d_in[3];
    const float* w_mask  = (const float*)d_in[4];

    float* out_f = (float*)d_out;
    float* x_mut = (float*)d_in[0];                     // dead-region scratch

    float*          pg  = out_f;                        // phi then g, 8 MB
    float*          sc  = out_f + 2097152;              // fp32 score slots, 4 MB
    unsigned short* y_u = (unsigned short*)(out_f + 3145728);  // y bf16, 4 MB

    // 1: phi
    hipLaunchKernelGGL(conv1x1_kernel, dim3(64, 2, 4), dim3(256), 0, stream,
                       x, w_phi, pg);
    // 2: scores (theta fused on the fly)
    hipLaunchKernelGGL(scores_kernel, dim3(4096, 4), dim3(256), 0, stream,
                       x, w_theta, pg, sc);
    // 3: softmax over h
    hipLaunchKernelGGL(softmax_kernel, dim3(3136), dim3(256), 0, stream, sc);
    // 4: g (overwrites phi)
    hipLaunchKernelGGL(conv1x1_kernel, dim3(64, 2, 4), dim3(256), 0, stream,
                       x, w_g, pg);
    // 5: aggregate -> y bf16
    hipLaunchKernelGGL(aggregate_kernel, dim3(4096, 4), dim3(128), 0, stream,
                       sc, pg, y_u);
    // 6: maskconv batches 0,1 -> out_f [0, 2097152)
    hipLaunchKernelGGL(maskconv_kernel, dim3(64, 4, 2), dim3(256), 0, stream,
                       x, w_mask, y_u, 0, out_f);
    // 7: spill y[2],y[3] (bytes [14M,16M)) into x's dead batch-0 region
    hipLaunchKernelGGL(copy2mb_kernel, dim3(512), dim3(256), 0, stream,
                       (const uint4*)(y_u + 1048576), (uint4*)x_mut);
    // 8: maskconv batches 2,3 -> out_f [2097152, 4194304)
    hipLaunchKernelGGL(maskconv_kernel, dim3(64, 4, 2), dim3(256), 0, stream,
                       x, w_mask, (const unsigned short*)x_mut, 2, out_f);
}

// Round 5
// 296.865 us; speedup vs baseline: 1.7411x; 1.7411x over previous
//
#include <hip/hip_runtime.h>

// Problem: b=4, c=256, ci=128, h=w=64 (HW=4096), field=7, kk=49. fp32 I/O.
//
// ZERO d_ws usage. Staging inside d_out (16 MB, float idx):
//   A = out_f[0,2097152)        : phi fp32 [4][128][4096]; later g overwrites
//   B = out_f[2097152,3145728)  : theta bf16 [4][4096][128]; later y bf16
//   C = out_f[3145728,4194304)  : scores fp32 slots [16384][64] (49 used)
// Phases: 1 phi->A, 2 theta->B, 3 scores(A,B)->C, 4 softmax C, 5 g->A,
// 6 aggregate(C,A)->B, 7 maskconv b01 -> out[0,8MB), 8 copy y b23 -> x[0]
// (dead), 9 maskconv b23 -> out[8MB,16MB).

__device__ __forceinline__ float bf2f(unsigned short u) {
    union { unsigned int i; float f; } v; v.i = ((unsigned int)u) << 16; return v.f;
}
__device__ __forceinline__ unsigned short f2bf(float f) {
    union { float f; unsigned int i; } v; v.f = f;
    unsigned int r = v.i + 0x7FFFu + ((v.i >> 16) & 1u);
    return (unsigned short)(r >> 16);
}

// ---------------------------------------------------------------------------
// conv1x1: dst[b,n,p] = sum_k W[n,k] * x[b,k,p], n in [0,128), K=256, fp32 out.
// BM=64 x BN=64 x BK=16, 256 threads, 4x4 microtile. Used for phi and g.
// ---------------------------------------------------------------------------
__global__ __launch_bounds__(256) void conv1x1_kernel(
    const float* __restrict__ x,
    const float* __restrict__ W,
    float* __restrict__ dst)
{
    const int tid = threadIdx.x;
    const int pt = blockIdx.x;
    const int nt = blockIdx.y;
    const int b  = blockIdx.z;
    const int nrow0 = nt * 64;

    __shared__ __align__(16) float sW[16 * 68];
    __shared__ __align__(16) float sX[16 * 68];

    const int tx = tid & 15;
    const int ty = tid >> 4;
    float acc[4][4] = {};

    for (int kt = 0; kt < 16; ++kt) {
        #pragma unroll
        for (int e = 0; e < 4; ++e) {
            int lin = tid + e * 256;
            int kk = lin & 15, nn = lin >> 4;
            sW[kk * 68 + nn] = W[(nrow0 + nn) * 256 + kt * 16 + kk];
        }
        #pragma unroll
        for (int e = 0; e < 4; ++e) {
            int lin = tid + e * 256;
            int pp = lin & 63, kk = lin >> 6;
            sX[kk * 68 + pp] = x[(b * 256 + kt * 16 + kk) * 4096 + pt * 64 + pp];
        }
        __syncthreads();
        #pragma unroll
        for (int kk = 0; kk < 16; ++kk) {
            const float4 wv = *reinterpret_cast<const float4*>(&sW[kk * 68 + ty * 4]);
            const float4 xv = *reinterpret_cast<const float4*>(&sX[kk * 68 + tx * 4]);
            const float wr[4] = {wv.x, wv.y, wv.z, wv.w};
            const float xr[4] = {xv.x, xv.y, xv.z, xv.w};
            #pragma unroll
            for (int r = 0; r < 4; ++r)
                #pragma unroll
                for (int e = 0; e < 4; ++e)
                    acc[r][e] = fmaf(wr[r], xr[e], acc[r][e]);
        }
        __syncthreads();
    }

    const int p0 = pt * 64 + tx * 4;
    #pragma unroll
    for (int r = 0; r < 4; ++r) {
        float4 v = make_float4(acc[r][0], acc[r][1], acc[r][2], acc[r][3]);
        *reinterpret_cast<float4*>(&dst[(b * 128 + nrow0 + ty * 4 + r) * 4096 + p0]) = v;
    }
}

// ---------------------------------------------------------------------------
// conv1x1t: theta, same GEMM but bf16 TRANSPOSED store: dst_t[b][p][cc].
// ---------------------------------------------------------------------------
__global__ __launch_bounds__(256) void conv1x1t_kernel(
    const float* __restrict__ x,
    const float* __restrict__ W,
    unsigned short* __restrict__ dst_t)
{
    const int tid = threadIdx.x;
    const int pt = blockIdx.x;
    const int nt = blockIdx.y;
    const int b  = blockIdx.z;
    const int nrow0 = nt * 64;

    __shared__ __align__(16) float sW[16 * 68];
    __shared__ __align__(16) float sX[16 * 68];

    const int tx = tid & 15;
    const int ty = tid >> 4;
    float acc[4][4] = {};

    for (int kt = 0; kt < 16; ++kt) {
        #pragma unroll
        for (int e = 0; e < 4; ++e) {
            int lin = tid + e * 256;
            int kk = lin & 15, nn = lin >> 4;
            sW[kk * 68 + nn] = W[(nrow0 + nn) * 256 + kt * 16 + kk];
        }
        #pragma unroll
        for (int e = 0; e < 4; ++e) {
            int lin = tid + e * 256;
            int pp = lin & 63, kk = lin >> 6;
            sX[kk * 68 + pp] = x[(b * 256 + kt * 16 + kk) * 4096 + pt * 64 + pp];
        }
        __syncthreads();
        #pragma unroll
        for (int kk = 0; kk < 16; ++kk) {
            const float4 wv = *reinterpret_cast<const float4*>(&sW[kk * 68 + ty * 4]);
            const float4 xv = *reinterpret_cast<const float4*>(&sX[kk * 68 + tx * 4]);
            const float wr[4] = {wv.x, wv.y, wv.z, wv.w};
            const float xr[4] = {xv.x, xv.y, xv.z, xv.w};
            #pragma unroll
            for (int r = 0; r < 4; ++r)
                #pragma unroll
                for (int e = 0; e < 4; ++e)
                    acc[r][e] = fmaf(wr[r], xr[e], acc[r][e]);
        }
        __syncthreads();
    }

    const int p0 = pt * 64 + tx * 4;
    const int cc0 = nrow0 + ty * 4;
    #pragma unroll
    for (int e = 0; e < 4; ++e) {
        ushort4 v;
        v.x = f2bf(acc[0][e]); v.y = f2bf(acc[1][e]);
        v.z = f2bf(acc[2][e]); v.w = f2bf(acc[3][e]);
        *reinterpret_cast<ushort4*>(&dst_t[(b * 4096 + p0 + e) * 128 + cc0]) = v;
    }
}

// ---------------------------------------------------------------------------
// scores v2: one WAVE per pixel s, lane = t (t<49 active).
// scores[b,s,t] = sum_cc th[s,cc] * phi_patch(F = s*6272 + cc*49 + t).
// Lanes consecutive in t -> p consecutive -> coalesced phi reads.
// th[cc] LDS read is same-address broadcast (no bank conflicts).
// ---------------------------------------------------------------------------
__global__ __launch_bounds__(256) void scores_kernel(
    const float* __restrict__ phi,
    const unsigned short* __restrict__ theta_t,
    float* __restrict__ scores)
{
    const int wv = threadIdx.x >> 6;
    const int ln = threadIdx.x & 63;
    const int s = blockIdx.x * 4 + wv;
    const int b = blockIdx.y;

    __shared__ float th[4][128];
    th[wv][ln]      = bf2f(theta_t[(b * 4096 + s) * 128 + ln]);
    th[wv][ln + 64] = bf2f(theta_t[(b * 4096 + s) * 128 + ln + 64]);
    __syncthreads();

    const float* __restrict__ phib = phi + b * 524288;
    float acc = 0.f;
    unsigned F = (unsigned)s * 6272u + (unsigned)ln;
    #pragma unroll 4
    for (int cc = 0; cc < 128; ++cc, F += 49u) {
        unsigned ch = F >> 12;
        unsigned p  = F & 4095u;
        unsigned c0 = ch / 49u;        // compiler magic-mul
        unsigned k  = ch - c0 * 49u;
        unsigned kh = k / 7u;
        unsigned kw = k - kh * 7u;
        int sy = (int)(p >> 6) + (int)kh - 3;
        int sx = (int)(p & 63u) + (int)kw - 3;
        float v = 0.f;
        if (ln < 49 && (unsigned)sy < 64u && (unsigned)sx < 64u)
            v = phib[c0 * 4096u + (unsigned)sy * 64u + (unsigned)sx];
        acc = fmaf(th[wv][cc], v, acc);
    }
    if (ln < 49) scores[(b * 4096 + s) * 64 + ln] = acc;
}

// ---------------------------------------------------------------------------
// softmax v2 over h (axis=1): block per (b,j); LDS-transpose 64(i) x 49(t)
// tile; contiguous 196B row loads/stores instead of 16KB-stride gathers.
// ---------------------------------------------------------------------------
__global__ __launch_bounds__(256) void softmax_kernel(float* __restrict__ scores)
{
    const int b = blockIdx.x >> 6;
    const int j = blockIdx.x & 63;
    const int tid = threadIdx.x;
    const int wv = tid >> 6;
    const int ln = tid & 63;

    __shared__ float tile[64][52];
    __shared__ float inv[52];

    #pragma unroll
    for (int it = 0; it < 16; ++it) {
        int i = it * 4 + wv;
        if (ln < 49) tile[i][ln] = scores[(b * 4096 + i * 64 + j) * 64 + ln];
    }
    __syncthreads();

    if (tid < 49) {
        float m = -3.4e38f;
        #pragma unroll 8
        for (int i = 0; i < 64; ++i) m = fmaxf(m, tile[i][tid]);
        float sum = 0.f;
        #pragma unroll 8
        for (int i = 0; i < 64; ++i) {
            float e = __expf(tile[i][tid] - m);
            tile[i][tid] = e;
            sum += e;
        }
        inv[tid] = 1.f / sum;
    }
    __syncthreads();

    #pragma unroll
    for (int it = 0; it < 16; ++it) {
        int i = it * 4 + wv;
        if (ln < 49) scores[(b * 4096 + i * 64 + j) * 64 + ln] = tile[i][ln] * inv[ln];
    }
}

// ---------------------------------------------------------------------------
// aggregate: y[b,s,cc] = sum_t attn[b,s,t] * g_patch(F = s*6272 + t*128 + cc)
// lane = cc -> F consecutive -> coalesced g reads. y bf16 into B region.
// ---------------------------------------------------------------------------
__global__ __launch_bounds__(128) void aggregate_kernel(
    const float* __restrict__ scores,
    const float* __restrict__ g,
    unsigned short* __restrict__ y_bf)
{
    const int s = blockIdx.x;
    const int b = blockIdx.y;
    const int cc = threadIdx.x;

    __shared__ float at[49];
    if (cc < 49) at[cc] = scores[(b * 4096 + s) * 64 + cc];
    __syncthreads();

    const float* __restrict__ gb = g + b * 524288;
    unsigned F = (unsigned)s * 6272u + (unsigned)cc;
    float acc = 0.f;
    #pragma unroll 7
    for (int t = 0; t < 49; ++t, F += 128u) {
        unsigned ch = F >> 12;
        unsigned p  = F & 4095u;
        unsigned c0 = ch / 49u;
        unsigned k  = ch - c0 * 49u;
        unsigned kh = k / 7u;
        unsigned kw = k - kh * 7u;
        int sy = (int)(p >> 6) + (int)kh - 3;
        int sx = (int)(p & 63u) + (int)kw - 3;
        float v = 0.f;
        if ((unsigned)sy < 64u && (unsigned)sx < 64u)
            v = gb[c0 * 4096u + (unsigned)sy * 64u + (unsigned)sx];
        acc = fmaf(at[t], v, acc);
    }
    y_bf[(b * 4096 + s) * 128 + cc] = f2bf(acc);
}

// ---------------------------------------------------------------------------
// maskconv: out[b,o,p] = x[b,o,p] + sum_cc w_mask[o,cc] * y[b,p,cc]
// b = b0 + blockIdx.z; y_src indexed with LOCAL batch. fp32 out.
// ---------------------------------------------------------------------------
__global__ __launch_bounds__(256) void maskconv_kernel(
    const float* __restrict__ x,
    const float* __restrict__ w_mask,
    const unsigned short* __restrict__ y_src,
    int b0,
    float* __restrict__ out)
{
    const int tid = threadIdx.x;
    const int pt = blockIdx.x;
    const int ot = blockIdx.y;
    const int bl = blockIdx.z;
    const int b  = b0 + bl;

    __shared__ __align__(16) float sW[16 * 68];
    __shared__ __align__(16) float sX[16 * 68];

    const int tx = tid & 15;
    const int ty = tid >> 4;
    float acc[4][4] = {};

    for (int kt = 0; kt < 8; ++kt) {
        #pragma unroll
        for (int e = 0; e < 4; ++e) {
            int lin = tid + e * 256;
            int kk = lin & 15, nn = lin >> 4;
            sW[kk * 68 + nn] = w_mask[(ot * 64 + nn) * 128 + kt * 16 + kk];
        }
        #pragma unroll
        for (int e = 0; e < 4; ++e) {
            int lin = tid + e * 256;
            int kk = lin & 15, pp = lin >> 4;
            sX[kk * 68 + pp] =
                bf2f(y_src[(bl * 4096 + pt * 64 + pp) * 128 + kt * 16 + kk]);
        }
        __syncthreads();
        #pragma unroll
        for (int kk = 0; kk < 16; ++kk) {
            const float4 wv = *reinterpret_cast<const float4*>(&sW[kk * 68 + ty * 4]);
            const float4 xv = *reinterpret_cast<const float4*>(&sX[kk * 68 + tx * 4]);
            const float wr[4] = {wv.x, wv.y, wv.z, wv.w};
            const float xr[4] = {xv.x, xv.y, xv.z, xv.w};
            #pragma unroll
            for (int r = 0; r < 4; ++r)
                #pragma unroll
                for (int e = 0; e < 4; ++e)
                    acc[r][e] = fmaf(wr[r], xr[e], acc[r][e]);
        }
        __syncthreads();
    }

    const int p0 = pt * 64 + tx * 4;
    #pragma unroll
    for (int r = 0; r < 4; ++r) {
        const int o = ot * 64 + ty * 4 + r;
        const int ofs = (b * 256 + o) * 4096 + p0;
        const float4 xr4 = *reinterpret_cast<const float4*>(&x[ofs]);
        float4 v = make_float4(acc[r][0] + xr4.x, acc[r][1] + xr4.y,
                               acc[r][2] + xr4.z, acc[r][3] + xr4.w);
        *reinterpret_cast<float4*>(&out[ofs]) = v;
    }
}

// 2 MB copy: y batches 2,3 -> x batch-0 scratch. 131072 uint4's.
__global__ __launch_bounds__(256) void copy2mb_kernel(
    const uint4* __restrict__ src, uint4* __restrict__ dst)
{
    const int i = blockIdx.x * 256 + threadIdx.x;
    dst[i] = src[i];
}

extern "C" void kernel_launch(void* const* d_in, const int* in_sizes, int n_in,
                              void* d_out, int out_size, void* d_ws, size_t ws_size,
                              hipStream_t stream) {
    const float* x       = (const float*)d_in[0];
    const float* w_phi   = (const float*)d_in[1];
    const float* w_theta = (const float*)d_in[2];
    const float* w_g     = (const float*)d_in[3];
    const float* w_mask  = (const float*)d_in[4];

    float* out_f = (float*)d_out;
    float* x_mut = (float*)d_in[0];                    // dead-region scratch

    float*          A = out_f;                                   // phi/g fp32
    unsigned short* B = (unsigned short*)(out_f + 2097152);      // theta/y bf16
    float*          C = out_f + 3145728;                         // score slots

    // 1: phi -> A
    hipLaunchKernelGGL(conv1x1_kernel, dim3(64, 2, 4), dim3(256), 0, stream,
                       x, w_phi, A);
    // 2: theta (transposed bf16) -> B
    hipLaunchKernelGGL(conv1x1t_kernel, dim3(64, 2, 4), dim3(256), 0, stream,
                       x, w_theta, B);
    // 3: scores -> C
    hipLaunchKernelGGL(scores_kernel, dim3(1024, 4), dim3(256), 0, stream,
                       A, B, C);
    // 4: softmax over h, in place
    hipLaunchKernelGGL(softmax_kernel, dim3(256), dim3(256), 0, stream, C);
    // 5: g -> A (phi dead)
    hipLaunchKernelGGL(conv1x1_kernel, dim3(64, 2, 4), dim3(256), 0, stream,
                       x, w_g, A);
    // 6: aggregate -> y bf16 into B (theta dead)
    hipLaunchKernelGGL(aggregate_kernel, dim3(4096, 4), dim3(128), 0, stream,
                       C, A, B);
    // 7: maskconv batches 0,1 -> out_f [0, 2097152)
    hipLaunchKernelGGL(maskconv_kernel, dim3(64, 4, 2), dim3(256), 0, stream,
                       x, w_mask, B, 0, out_f);
    // 8: spill y batches 2,3 into x's dead batch-0 region
    hipLaunchKernelGGL(copy2mb_kernel, dim3(512), dim3(256), 0, stream,
                       (const uint4*)(B + 1048576), (uint4*)x_mut);
    // 9: maskconv batches 2,3 -> out_f [2097152, 4194304)
    hipLaunchKernelGGL(maskconv_kernel, dim3(64, 4, 2), dim3(256), 0, stream,
                       x, w_mask, (const unsigned short*)x_mut, 2, out_f);
}

// Round 6
// 235.799 us; speedup vs baseline: 2.1920x; 1.2590x over previous
//
#include <hip/hip_runtime.h>

// Problem: b=4, c=256, ci=128, h=w=64 (HW=4096), field=7, kk=49. fp32 I/O.
//
// Padded-plane trick: phi/g stored bf16 as [b][c0][70][72] planes, zero
// borders, data (py,px) at row py+3, col px+4. Patch value for flat decode
// F -> (ch,p) is plane[OFF(ch) + p + 8*(p>>6)] with
// OFF(ch) = c0*5040 + kh*72 + kw + 1  (c0=ch/49, kh=(ch%49)/7, kw=ch%7),
// NO bounds check needed. Per-pixel F-range spans <2*4096 so ch takes <=3
// values; loop split into 3 pure + 2 mixed segments (wave-uniform OFF).
//
// d_out (16 MB = 4,194,304 floats) staging:
//   A @ f[0, 1,290,240)          padded bf16 phi, then g   (2,580,480 ush)
//   C @ f[1,290,240, 2,338,816)  fp32 score slots [b][s][64] (49 used)
//   B @ f[2,338,816, 3,387,392)  bf16 theta [b][s][128], then y
// Phases: zeroA, phi->A, theta->B, scores(A,B)->C, softmax C, g->A,
// aggregate(C,A)->B(y), maskconv b01 -> out[0,8MB) (y b01 not in range),
// copy y b23 -> x batch-0 (dead), maskconv b23 -> out[8MB,16MB).

#define A_F_OFF   0
#define C_F_OFF   1290240
#define B_F_OFF   2338816
#define A_BATCH   645120      // ush per batch in A
#define PLANE     5040        // 70*72 ush per c0 plane

__device__ __forceinline__ float bf2f(unsigned short u) {
    union { unsigned int i; float f; } v; v.i = ((unsigned int)u) << 16; return v.f;
}
__device__ __forceinline__ unsigned short f2bf(float f) {
    union { float f; unsigned int i; } v; v.f = f;
    unsigned int r = v.i + 0x7FFFu + ((v.i >> 16) & 1u);
    return (unsigned short)(r >> 16);
}

// zero the whole A region (borders must be 0; ws/out are poisoned each launch)
__global__ __launch_bounds__(256) void zeroA_kernel(uint4* __restrict__ dst) {
    dst[blockIdx.x * 256 + threadIdx.x] = make_uint4(0u, 0u, 0u, 0u);
}

// ---------------------------------------------------------------------------
// conv_pad: dst plane-padded bf16. dst[b][n][py+3][px+4] = sum_k W[n,k]x[b,k,p]
// BM=64(n) x BN=64(p) x BK=16, 256 threads, 4x4 microtile.
// ---------------------------------------------------------------------------
__global__ __launch_bounds__(256) void conv_pad_kernel(
    const float* __restrict__ x,
    const float* __restrict__ W,
    unsigned short* __restrict__ A_u)
{
    const int tid = threadIdx.x;
    const int pt = blockIdx.x;   // = py (64 rows)
    const int nt = blockIdx.y;
    const int b  = blockIdx.z;
    const int nrow0 = nt * 64;

    __shared__ __align__(16) float sW[16 * 68];
    __shared__ __align__(16) float sX[16 * 68];

    const int tx = tid & 15;
    const int ty = tid >> 4;
    float acc[4][4] = {};

    for (int kt = 0; kt < 16; ++kt) {
        #pragma unroll
        for (int e = 0; e < 4; ++e) {
            int lin = tid + e * 256;
            int kk = lin & 15, nn = lin >> 4;
            sW[kk * 68 + nn] = W[(nrow0 + nn) * 256 + kt * 16 + kk];
        }
        #pragma unroll
        for (int e = 0; e < 4; ++e) {
            int lin = tid + e * 256;
            int pp = lin & 63, kk = lin >> 6;
            sX[kk * 68 + pp] = x[(b * 256 + kt * 16 + kk) * 4096 + pt * 64 + pp];
        }
        __syncthreads();
        #pragma unroll
        for (int kk = 0; kk < 16; ++kk) {
            const float4 wv = *reinterpret_cast<const float4*>(&sW[kk * 68 + ty * 4]);
            const float4 xv = *reinterpret_cast<const float4*>(&sX[kk * 68 + tx * 4]);
            const float wr[4] = {wv.x, wv.y, wv.z, wv.w};
            const float xr[4] = {xv.x, xv.y, xv.z, xv.w};
            #pragma unroll
            for (int r = 0; r < 4; ++r)
                #pragma unroll
                for (int e = 0; e < 4; ++e)
                    acc[r][e] = fmaf(wr[r], xr[e], acc[r][e]);
        }
        __syncthreads();
    }

    // store: row py+3 = pt+3, col px+4 = tx*4+4 (8B-aligned ushort4)
    const unsigned wbase = (unsigned)(b * A_BATCH + (pt + 3) * 72 + tx * 4 + 4);
    #pragma unroll
    for (int r = 0; r < 4; ++r) {
        const int n = nrow0 + ty * 4 + r;
        ushort4 v;
        v.x = f2bf(acc[r][0]); v.y = f2bf(acc[r][1]);
        v.z = f2bf(acc[r][2]); v.w = f2bf(acc[r][3]);
        *reinterpret_cast<ushort4*>(&A_u[wbase + (unsigned)n * PLANE]) = v;
    }
}

// ---------------------------------------------------------------------------
// conv1x1t: theta, bf16 TRANSPOSED store dst_t[b][p][cc].
// ---------------------------------------------------------------------------
__global__ __launch_bounds__(256) void conv1x1t_kernel(
    const float* __restrict__ x,
    const float* __restrict__ W,
    unsigned short* __restrict__ dst_t)
{
    const int tid = threadIdx.x;
    const int pt = blockIdx.x;
    const int nt = blockIdx.y;
    const int b  = blockIdx.z;
    const int nrow0 = nt * 64;

    __shared__ __align__(16) float sW[16 * 68];
    __shared__ __align__(16) float sX[16 * 68];

    const int tx = tid & 15;
    const int ty = tid >> 4;
    float acc[4][4] = {};

    for (int kt = 0; kt < 16; ++kt) {
        #pragma unroll
        for (int e = 0; e < 4; ++e) {
            int lin = tid + e * 256;
            int kk = lin & 15, nn = lin >> 4;
            sW[kk * 68 + nn] = W[(nrow0 + nn) * 256 + kt * 16 + kk];
        }
        #pragma unroll
        for (int e = 0; e < 4; ++e) {
            int lin = tid + e * 256;
            int pp = lin & 63, kk = lin >> 6;
            sX[kk * 68 + pp] = x[(b * 256 + kt * 16 + kk) * 4096 + pt * 64 + pp];
        }
        __syncthreads();
        #pragma unroll
        for (int kk = 0; kk < 16; ++kk) {
            const float4 wv = *reinterpret_cast<const float4*>(&sW[kk * 68 + ty * 4]);
            const float4 xv = *reinterpret_cast<const float4*>(&sX[kk * 68 + tx * 4]);
            const float wr[4] = {wv.x, wv.y, wv.z, wv.w};
            const float xr[4] = {xv.x, xv.y, xv.z, xv.w};
            #pragma unroll
            for (int r = 0; r < 4; ++r)
                #pragma unroll
                for (int e = 0; e < 4; ++e)
                    acc[r][e] = fmaf(wr[r], xr[e], acc[r][e]);
        }
        __syncthreads();
    }

    const int p0 = pt * 64 + tx * 4;
    const int cc0 = nrow0 + ty * 4;
    #pragma unroll
    for (int e = 0; e < 4; ++e) {
        ushort4 v;
        v.x = f2bf(acc[0][e]); v.y = f2bf(acc[1][e]);
        v.z = f2bf(acc[2][e]); v.w = f2bf(acc[3][e]);
        *reinterpret_cast<ushort4*>(&dst_t[(b * 4096 + p0 + e) * 128 + cc0]) = v;
    }
}

// ---------------------------------------------------------------------------
// scores v3: wave per pixel s, lane = t. 3 pure + 2 mixed cc-segments;
// padded planes -> no bounds check, addr = OFF + p + 8*(p>>6).
// ---------------------------------------------------------------------------
__global__ __launch_bounds__(256) void scores_kernel(
    const unsigned short* __restrict__ Apad,
    const unsigned short* __restrict__ theta_bf,
    float* __restrict__ scores)
{
    const int w  = threadIdx.x >> 6;
    const int ln = threadIdx.x & 63;
    const int s  = blockIdx.x * 4 + w;
    const int b  = blockIdx.y;

    __shared__ float th[4][128];
    {
        const unsigned short* tb = theta_bf + (b * 4096 + s) * 128;
        th[w][ln]      = bf2f(tb[ln]);
        th[w][ln + 64] = bf2f(tb[ln + 64]);
    }
    __syncthreads();

    const unsigned short* __restrict__ Ab = Apad + b * A_BATCH;

    const int base  = s * 6272;
    const int ch_lo = base >> 12;
    const unsigned B1 = (unsigned)(ch_lo + 1) << 12;
    const unsigned B2 = (unsigned)(ch_lo + 2) << 12;
    const int d1 = (int)B1 - base;          // in (0, 4096]
    const int d2 = d1 + 4096;

    int A1 = d1 / 49;
    int A2 = (d1 + 48) / 49;
    int C1 = d2 / 49;        if (C1 > 128) C1 = 128;
    int C2 = (d2 + 48) / 49; if (C2 > 128) C2 = 128;

    unsigned OFFv[3];
    #pragma unroll
    for (int i = 0; i < 3; ++i) {
        int ch = ch_lo + i;
        int c0 = ch / 49; if (c0 > 127) c0 = 127;
        int rr = ch - c0 * 49;
        int kh = rr / 7;
        int kw = rr - kh * 7;
        OFFv[i] = (unsigned)(c0 * PLANE + kh * 72 + kw + 1);
    }

    unsigned F = (unsigned)(base + ln);   // t = ln (lanes >=49 are ghosts)
    float acc = 0.f;

    {   // segment 0: pure OFF0
        const unsigned OFF_ = OFFv[0];
        #pragma unroll 4
        for (int cc = 0; cc < A1; ++cc) {
            unsigned p = F & 4095u;
            unsigned a = OFF_ + p + ((p >> 6) << 3);
            acc = fmaf(th[w][cc], bf2f(Ab[a]), acc);
            F += 49u;
        }
    }
    for (int cc = A1; cc < A2; ++cc) {    // mixed B1 (<=1 iter)
        unsigned OFF_ = (F >= B1) ? OFFv[1] : OFFv[0];
        unsigned p = F & 4095u;
        unsigned a = OFF_ + p + ((p >> 6) << 3);
        acc = fmaf(th[w][cc], bf2f(Ab[a]), acc);
        F += 49u;
    }
    {   // segment 1: pure OFF1
        const unsigned OFF_ = OFFv[1];
        #pragma unroll 4
        for (int cc = A2; cc < C1; ++cc) {
            unsigned p = F & 4095u;
            unsigned a = OFF_ + p + ((p >> 6) << 3);
            acc = fmaf(th[w][cc], bf2f(Ab[a]), acc);
            F += 49u;
        }
    }
    for (int cc = C1; cc < C2; ++cc) {    // mixed B2 (<=1 iter)
        unsigned OFF_ = (F >= B2) ? OFFv[2] : OFFv[1];
        unsigned p = F & 4095u;
        unsigned a = OFF_ + p + ((p >> 6) << 3);
        acc = fmaf(th[w][cc], bf2f(Ab[a]), acc);
        F += 49u;
    }
    {   // segment 2: pure OFF2
        const unsigned OFF_ = OFFv[2];
        #pragma unroll 4
        for (int cc = C2; cc < 128; ++cc) {
            unsigned p = F & 4095u;
            unsigned a = OFF_ + p + ((p >> 6) << 3);
            acc = fmaf(th[w][cc], bf2f(Ab[a]), acc);
            F += 49u;
        }
    }

    if (ln < 49) scores[(b * 4096 + s) * 64 + ln] = acc;
}

// ---------------------------------------------------------------------------
// softmax over h (axis=1): block per (b,j); LDS-transpose 64(i) x 49(t).
// ---------------------------------------------------------------------------
__global__ __launch_bounds__(256) void softmax_kernel(float* __restrict__ scores)
{
    const int b = blockIdx.x >> 6;
    const int j = blockIdx.x & 63;
    const int tid = threadIdx.x;
    const int wv = tid >> 6;
    const int ln = tid & 63;

    __shared__ float tile[64][52];
    __shared__ float inv[52];

    #pragma unroll
    for (int it = 0; it < 16; ++it) {
        int i = it * 4 + wv;
        if (ln < 49) tile[i][ln] = scores[(b * 4096 + i * 64 + j) * 64 + ln];
    }
    __syncthreads();

    if (tid < 49) {
        float m = -3.4e38f;
        #pragma unroll 8
        for (int i = 0; i < 64; ++i) m = fmaxf(m, tile[i][tid]);
        float sum = 0.f;
        #pragma unroll 8
        for (int i = 0; i < 64; ++i) {
            float e = __expf(tile[i][tid] - m);
            tile[i][tid] = e;
            sum += e;
        }
        inv[tid] = 1.f / sum;
    }
    __syncthreads();

    #pragma unroll
    for (int it = 0; it < 16; ++it) {
        int i = it * 4 + wv;
        if (ln < 49) scores[(b * 4096 + i * 64 + j) * 64 + ln] = tile[i][ln] * inv[ln];
    }
}

// ---------------------------------------------------------------------------
// aggregate v3: 2 pixels/block, lane = cc (128). Same segment trick over t
// (stride 128 > cc-span 127). y bf16 into B.
// ---------------------------------------------------------------------------
__global__ __launch_bounds__(256) void aggregate_kernel(
    const float* __restrict__ scores,
    const unsigned short* __restrict__ Apad,
    unsigned short* __restrict__ y_bf)
{
    const int pix = threadIdx.x >> 7;
    const int cc  = threadIdx.x & 127;
    const int s   = blockIdx.x * 2 + pix;
    const int b   = blockIdx.y;

    __shared__ float at[2][52];
    if (cc < 49) at[pix][cc] = scores[(b * 4096 + s) * 64 + cc];
    __syncthreads();

    const unsigned short* __restrict__ Ab = Apad + b * A_BATCH;

    const int base  = s * 6272;
    const int ch_lo = base >> 12;
    const unsigned B1 = (unsigned)(ch_lo + 1) << 12;
    const unsigned B2 = (unsigned)(ch_lo + 2) << 12;
    const int d1 = (int)B1 - base;
    const int d2 = d1 + 4096;

    int A1 = d1 >> 7;
    int A2 = (d1 + 127) >> 7;
    int C1 = d2 >> 7;          if (C1 > 49) C1 = 49;
    int C2 = (d2 + 127) >> 7;  if (C2 > 49) C2 = 49;
    if (A1 > 49) A1 = 49;
    if (A2 > 49) A2 = 49;

    unsigned OFFv[3];
    #pragma unroll
    for (int i = 0; i < 3; ++i) {
        int ch = ch_lo + i;
        int c0 = ch / 49; if (c0 > 127) c0 = 127;
        int rr = ch - c0 * 49;
        int kh = rr / 7;
        int kw = rr - kh * 7;
        OFFv[i] = (unsigned)(c0 * PLANE + kh * 72 + kw + 1);
    }

    unsigned F = (unsigned)(base + cc);
    float acc = 0.f;

    {
        const unsigned OFF_ = OFFv[0];
        #pragma unroll 4
        for (int t = 0; t < A1; ++t) {
            unsigned p = F & 4095u;
            unsigned a = OFF_ + p + ((p >> 6) << 3);
            acc = fmaf(at[pix][t], bf2f(Ab[a]), acc);
            F += 128u;
        }
    }
    for (int t = A1; t < A2; ++t) {
        unsigned OFF_ = (F >= B1) ? OFFv[1] : OFFv[0];
        unsigned p = F & 4095u;
        unsigned a = OFF_ + p + ((p >> 6) << 3);
        acc = fmaf(at[pix][t], bf2f(Ab[a]), acc);
        F += 128u;
    }
    {
        const unsigned OFF_ = OFFv[1];
        #pragma unroll 4
        for (int t = A2; t < C1; ++t) {
            unsigned p = F & 4095u;
            unsigned a = OFF_ + p + ((p >> 6) << 3);
            acc = fmaf(at[pix][t], bf2f(Ab[a]), acc);
            F += 128u;
        }
    }
    for (int t = C1; t < C2; ++t) {
        unsigned OFF_ = (F >= B2) ? OFFv[2] : OFFv[1];
        unsigned p = F & 4095u;
        unsigned a = OFF_ + p + ((p >> 6) << 3);
        acc = fmaf(at[pix][t], bf2f(Ab[a]), acc);
        F += 128u;
    }
    {
        const unsigned OFF_ = OFFv[2];
        for (int t = C2; t < 49; ++t) {
            unsigned p = F & 4095u;
            unsigned a = OFF_ + p + ((p >> 6) << 3);
            acc = fmaf(at[pix][t], bf2f(Ab[a]), acc);
            F += 128u;
        }
    }

    y_bf[(b * 4096 + s) * 128 + cc] = f2bf(acc);
}

// ---------------------------------------------------------------------------
// maskconv: out[b,o,p] = x[b,o,p] + sum_cc w_mask[o,cc] * y[b,p,cc]
// b = b0 + blockIdx.z; y_src indexed with LOCAL batch. fp32 out.
// ---------------------------------------------------------------------------
__global__ __launch_bounds__(256) void maskconv_kernel(
    const float* __restrict__ x,
    const float* __restrict__ w_mask,
    const unsigned short* __restrict__ y_src,
    int b0,
    float* __restrict__ out)
{
    const int tid = threadIdx.x;
    const int pt = blockIdx.x;
    const int ot = blockIdx.y;
    const int bl = blockIdx.z;
    const int b  = b0 + bl;

    __shared__ __align__(16) float sW[16 * 68];
    __shared__ __align__(16) float sX[16 * 68];

    const int tx = tid & 15;
    const int ty = tid >> 4;
    float acc[4][4] = {};

    for (int kt = 0; kt < 8; ++kt) {
        #pragma unroll
        for (int e = 0; e < 4; ++e) {
            int lin = tid + e * 256;
            int kk = lin & 15, nn = lin >> 4;
            sW[kk * 68 + nn] = w_mask[(ot * 64 + nn) * 128 + kt * 16 + kk];
        }
        #pragma unroll
        for (int e = 0; e < 4; ++e) {
            int lin = tid + e * 256;
            int kk = lin & 15, pp = lin >> 4;
            sX[kk * 68 + pp] =
                bf2f(y_src[(bl * 4096 + pt * 64 + pp) * 128 + kt * 16 + kk]);
        }
        __syncthreads();
        #pragma unroll
        for (int kk = 0; kk < 16; ++kk) {
            const float4 wv = *reinterpret_cast<const float4*>(&sW[kk * 68 + ty * 4]);
            const float4 xv = *reinterpret_cast<const float4*>(&sX[kk * 68 + tx * 4]);
            const float wr[4] = {wv.x, wv.y, wv.z, wv.w};
            const float xr[4] = {xv.x, xv.y, xv.z, xv.w};
            #pragma unroll
            for (int r = 0; r < 4; ++r)
                #pragma unroll
                for (int e = 0; e < 4; ++e)
                    acc[r][e] = fmaf(wr[r], xr[e], acc[r][e]);
        }
        __syncthreads();
    }

    const int p0 = pt * 64 + tx * 4;
    #pragma unroll
    for (int r = 0; r < 4; ++r) {
        const int o = ot * 64 + ty * 4 + r;
        const int ofs = (b * 256 + o) * 4096 + p0;
        const float4 xr4 = *reinterpret_cast<const float4*>(&x[ofs]);
        float4 v = make_float4(acc[r][0] + xr4.x, acc[r][1] + xr4.y,
                               acc[r][2] + xr4.z, acc[r][3] + xr4.w);
        *reinterpret_cast<float4*>(&out[ofs]) = v;
    }
}

// 2 MB copy: y batches 2,3 -> x batch-0 scratch. 131072 uint4's.
__global__ __launch_bounds__(256) void copy2mb_kernel(
    const uint4* __restrict__ src, uint4* __restrict__ dst)
{
    const int i = blockIdx.x * 256 + threadIdx.x;
    dst[i] = src[i];
}

extern "C" void kernel_launch(void* const* d_in, const int* in_sizes, int n_in,
                              void* d_out, int out_size, void* d_ws, size_t ws_size,
                              hipStream_t stream) {
    const float* x       = (const float*)d_in[0];
    const float* w_phi   = (const float*)d_in[1];
    const float* w_theta = (const float*)d_in[2];
    const float* w_g     = (const float*)d_in[3];
    const float* w_mask  = (const float*)d_in[4];

    float* out_f = (float*)d_out;
    float* x_mut = (float*)d_in[0];                       // dead-region scratch

    unsigned short* A_u = (unsigned short*)(out_f + A_F_OFF);
    float*          C_f = out_f + C_F_OFF;
    unsigned short* B_u = (unsigned short*)(out_f + B_F_OFF);

    // zero A (padded planes' borders must be 0)
    hipLaunchKernelGGL(zeroA_kernel, dim3(1260), dim3(256), 0, stream,
                       (uint4*)A_u);
    // phi (padded bf16) -> A
    hipLaunchKernelGGL(conv_pad_kernel, dim3(64, 2, 4), dim3(256), 0, stream,
                       x, w_phi, A_u);
    // theta (transposed bf16) -> B
    hipLaunchKernelGGL(conv1x1t_kernel, dim3(64, 2, 4), dim3(256), 0, stream,
                       x, w_theta, B_u);
    // scores -> C
    hipLaunchKernelGGL(scores_kernel, dim3(1024, 4), dim3(256), 0, stream,
                       A_u, B_u, C_f);
    // softmax over h, in place
    hipLaunchKernelGGL(softmax_kernel, dim3(256), dim3(256), 0, stream, C_f);
    // g (padded bf16) -> A (phi dead; borders still zero)
    hipLaunchKernelGGL(conv_pad_kernel, dim3(64, 2, 4), dim3(256), 0, stream,
                       x, w_g, A_u);
    // aggregate -> y bf16 into B (theta dead)
    hipLaunchKernelGGL(aggregate_kernel, dim3(2048, 4), dim3(256), 0, stream,
                       C_f, A_u, B_u);
    // maskconv batches 0,1 -> out_f [0, 2097152)   (y b01 lives above range)
    hipLaunchKernelGGL(maskconv_kernel, dim3(64, 4, 2), dim3(256), 0, stream,
                       x, w_mask, B_u, 0, out_f);
    // spill y batches 2,3 into x's dead batch-0 region
    hipLaunchKernelGGL(copy2mb_kernel, dim3(512), dim3(256), 0, stream,
                       (const uint4*)(B_u + 1048576), (uint4*)x_mut);
    // maskconv batches 2,3 -> out_f [2097152, 4194304)
    hipLaunchKernelGGL(maskconv_kernel, dim3(64, 4, 2), dim3(256), 0, stream,
                       x, w_mask, (const unsigned short*)x_mut, 2, out_f);
}